// Round 5
// baseline (114.769 us; speedup 1.0000x reference)
//
#include <hip/hip_runtime.h>

#define LOG2E 1.4426950408889634f

// B=4, C=64, HW=4096, HEADS=4, ch=16
// qb : [b][o][hw] f32, scaled by LOG2E   (o = h*16+ch)
// kT : [bh][j][ch16] bf16 (32B rows)
// vb : [b][o][hw] bf16
// ao : [bh][i][ch16] f32 == raw .view order [b][64][4096]

using s8v   = __attribute__((ext_vector_type(8))) short;
using u16x8 = __attribute__((ext_vector_type(8))) unsigned short;
using f32x4 = __attribute__((ext_vector_type(4))) float;

static __device__ __forceinline__ unsigned short bf16b(float f) {
  return __builtin_bit_cast(unsigned short, (__bf16)f);
}

__global__ __launch_bounds__(256) void qkv_proj(
    const float* __restrict__ x,
    const float* __restrict__ wq, const float* __restrict__ bq,
    const float* __restrict__ wk, const float* __restrict__ bk,
    const float* __restrict__ wv, const float* __restrict__ bv,
    float* __restrict__ qb, unsigned short* __restrict__ kT,
    unsigned short* __restrict__ vb) {
  __shared__ __align__(16) float xs[64][64];     // [c][px]
  __shared__ float wqs[64][65];                  // [c][o] transposed, padded
  __shared__ float wks[64][65];
  __shared__ float wvs[64][65];
  int t = threadIdx.x;
  int b = blockIdx.x >> 6;
  int px0 = (blockIdx.x & 63) << 6;
#pragma unroll
  for (int kk = 0; kk < 16; kk++) {
    int idx = kk * 256 + t;
    int c = idx >> 6, px = idx & 63;
    xs[c][px] = x[((size_t)(b * 64 + c) << 12) + px0 + px];
    int o = idx >> 6, c2 = idx & 63;
    wqs[c2][o] = wq[idx];
    wks[c2][o] = wk[idx];
    wvs[c2][o] = wv[idx];
  }
  __syncthreads();

  int o = t & 63;
  int pw = (t >> 6) << 4;
  float aq[16], ak[16], av[16];
#pragma unroll
  for (int p = 0; p < 16; p++) { aq[p] = 0.f; ak[p] = 0.f; av[p] = 0.f; }

  for (int c = 0; c < 64; c++) {
    float wqv = wqs[c][o], wkv = wks[c][o], wvv = wvs[c][o];
    float xr[16];
#pragma unroll
    for (int g = 0; g < 4; g++) {
      float4 x4 = *reinterpret_cast<const float4*>(&xs[c][pw + 4 * g]);
      xr[4 * g] = x4.x; xr[4 * g + 1] = x4.y; xr[4 * g + 2] = x4.z; xr[4 * g + 3] = x4.w;
    }
#pragma unroll
    for (int p = 0; p < 16; p++) {
      aq[p] += wqv * xr[p];
      ak[p] += wkv * xr[p];
      av[p] += wvv * xr[p];
    }
  }

  float bqv = bq[o], bkv = bk[o], bvv = bv[o];
  {
    float* dstq = qb + ((size_t)(b * 64 + o) << 12) + px0 + pw;
#pragma unroll
    for (int g = 0; g < 4; g++) {
      float4 q4 = { (aq[4 * g + 0] + bqv) * LOG2E, (aq[4 * g + 1] + bqv) * LOG2E,
                    (aq[4 * g + 2] + bqv) * LOG2E, (aq[4 * g + 3] + bqv) * LOG2E };
      reinterpret_cast<float4*>(dstq)[g] = q4;
    }
    // v: bf16 [b][o][hw]
    unsigned short* dstv = vb + ((size_t)(b * 64 + o) << 12) + px0 + pw;
    u16x8 v0, v1;
#pragma unroll
    for (int p = 0; p < 8; p++) {
      v0[p] = bf16b(av[p] + bvv);
      v1[p] = bf16b(av[8 + p] + bvv);
    }
    *reinterpret_cast<u16x8*>(dstv) = v0;
    *reinterpret_cast<u16x8*>(dstv + 8) = v1;
  }
  // k: bf16 [bh][j][ch]
  int bh = b * 4 + (o >> 4);
  int chn = o & 15;
  size_t kb = ((size_t)bh << 16) + ((size_t)(px0 + pw) << 4) + chn;
#pragma unroll
  for (int p = 0; p < 16; p++) {
    kT[kb + ((size_t)p << 4)] = bf16b(ak[p] + bkv);
  }
}

// MFMA flash attention, no max tracking (scores bounded; fixed M=0 softmax is
// exact in f32 range). grid = 2048 (16 bh x 128 i-tiles of 32 queries), block
// = 4 waves; wave w owns j-slice [w*1024, w*1024+1024). 8 blocks/CU -> 32
// waves/CU (full occupancy cap).
// Swapped QK^T: S^T = mfma(Kdup, [Qhi|Qlo]) -> lane(i_,q4) holds
// s0[r]=S[jb+4q4+r][i_], s1[r]=S[jb+16+4q4+r][i_].
// PV k-slot perm perm(8q4+e)= e<4 ? 4q4+e : 16+4q4+e-4 on BOTH V-A and P-B
// fragments -> P B-frag is the lane's own exp values; zero cross-lane traffic.
__global__ __launch_bounds__(256) void attn_mfma(
    const float* __restrict__ qb, const unsigned short* __restrict__ kT,
    const unsigned short* __restrict__ vb, float* __restrict__ ao) {
  __shared__ float red[4][32][18];
  const int tid  = threadIdx.x;
  const int w    = tid >> 6;
  const int lane = tid & 63;
  const int i_   = lane & 15;
  const int q4   = lane >> 4;
  const int chb  = (q4 & 1) << 3;

  // XCD swizzle: 2048 blocks, 256 consecutive per XCD -> 2 bh per XCD
  const int orig = ((blockIdx.x & 7) << 8) + (blockIdx.x >> 3);
  const int bh = orig >> 7;
  const int i0 = (orig & 127) << 5;
  const int b = bh >> 2, h = bh & 3;

  // Q fragments: B[k][n]: lane holds col n=i_, k = 8*q4+e.
  // k 0-15 -> Qhi (q4<2), k 16-31 -> Qlo (q4>=2); ch = chb+e.
  s8v BQ[2];
#pragma unroll
  for (int g = 0; g < 2; ++g) {
    const float* qp = qb + (((size_t)(b * 64 + h * 16 + chb)) << 12) + (i0 + (g << 4) + i_);
#pragma unroll
    for (int e = 0; e < 8; ++e) {
      float f = qp[(size_t)e << 12];
      __bf16 hi = (__bf16)f;
      float v = (q4 < 2) ? (float)hi : (f - (float)hi);
      BQ[g][e] = __builtin_bit_cast(short, (__bf16)v);
    }
  }

  f32x4 acc[2];
  float l[2];
#pragma unroll
  for (int g = 0; g < 2; ++g) {
    acc[g] = (f32x4){0.f, 0.f, 0.f, 0.f};
    l[g] = 0.f;
  }

  const unsigned short* vpb = vb + (((size_t)(b * 64 + h * 16 + i_)) << 12);
  const unsigned short* kpb = kT + ((size_t)bh << 16);

  for (int t = 0; t < 32; ++t) {
    const int jb = (w << 10) + (t << 5);
    // V A-frag with perm: lane row ch=i_, k=8q4+e -> j = jb + (e<4?4q4+e:16+4q4+e-4)
    s8v AV;
    {
      struct { uint2 a, b; } pair;
      pair.a = *(const uint2*)(vpb + jb + (q4 << 2));
      pair.b = *(const uint2*)(vpb + jb + 16 + (q4 << 2));
      AV = __builtin_bit_cast(s8v, pair);
    }
    // K A-frags (ch duplicated into k 16-31 via chb): row j'=i_ (+16 for AK1)
    s8v AK0 = *(const s8v*)(kpb + (((size_t)(jb + i_)) << 4) + chb);
    s8v AK1 = *(const s8v*)(kpb + (((size_t)(jb + 16 + i_)) << 4) + chb);

#pragma unroll
    for (int g = 0; g < 2; ++g) {
      f32x4 z = {0.f, 0.f, 0.f, 0.f};
      f32x4 s0 = __builtin_amdgcn_mfma_f32_16x16x32_bf16(AK0, BQ[g], z, 0, 0, 0);
      f32x4 s1 = __builtin_amdgcn_mfma_f32_16x16x32_bf16(AK1, BQ[g], z, 0, 0, 0);
      float p0 = __builtin_amdgcn_exp2f(s0[0]);
      float p1 = __builtin_amdgcn_exp2f(s0[1]);
      float p2 = __builtin_amdgcn_exp2f(s0[2]);
      float p3 = __builtin_amdgcn_exp2f(s0[3]);
      float p4 = __builtin_amdgcn_exp2f(s1[0]);
      float p5 = __builtin_amdgcn_exp2f(s1[1]);
      float p6 = __builtin_amdgcn_exp2f(s1[2]);
      float p7 = __builtin_amdgcn_exp2f(s1[3]);
      l[g] += (((p0 + p1) + (p2 + p3)) + ((p4 + p5) + (p6 + p7)));
      // P B-frag: lane col i_, k=8q4+e -> P[jb+perm][i_] = own p values, in order
      s8v PB;
      PB[0] = (short)bf16b(p0); PB[1] = (short)bf16b(p1);
      PB[2] = (short)bf16b(p2); PB[3] = (short)bf16b(p3);
      PB[4] = (short)bf16b(p4); PB[5] = (short)bf16b(p5);
      PB[6] = (short)bf16b(p6); PB[7] = (short)bf16b(p7);
      acc[g] = __builtin_amdgcn_mfma_f32_16x16x32_bf16(AV, PB, acc[g], 0, 0, 0);
    }
  }

  // per-wave results -> LDS merge across the 4 j-slices (pure sums)
#pragma unroll
  for (int g = 0; g < 2; ++g) {
    float lg = l[g];
    lg += __shfl_xor(lg, 16);
    lg += __shfl_xor(lg, 32);
    int iq = (g << 4) + i_;
    if (q4 == 0) red[w][iq][0] = lg;
    red[w][iq][1 + (q4 << 2) + 0] = acc[g][0];
    red[w][iq][1 + (q4 << 2) + 1] = acc[g][1];
    red[w][iq][1 + (q4 << 2) + 2] = acc[g][2];
    red[w][iq][1 + (q4 << 2) + 3] = acc[g][3];
  }
  __syncthreads();

  if (tid < 128) {
    int iq = tid & 31, quad = tid >> 5;
    float L = (red[0][iq][0] + red[1][iq][0]) + (red[2][iq][0] + red[3][iq][0]);
    float o0 = 0.f, o1 = 0.f, o2 = 0.f, o3 = 0.f;
#pragma unroll
    for (int s = 0; s < 4; ++s) {
      o0 += red[s][iq][1 + (quad << 2) + 0];
      o1 += red[s][iq][1 + (quad << 2) + 1];
      o2 += red[s][iq][1 + (quad << 2) + 2];
      o3 += red[s][iq][1 + (quad << 2) + 3];
    }
    float inv = 1.0f / L;
    float4 o = { o0 * inv, o1 * inv, o2 * inv, o3 * inv };
    *(float4*)&ao[((((size_t)bh << 12) + i0 + iq) << 4) + (quad << 2)] = o;
  }
}

__global__ __launch_bounds__(256) void out_proj(
    const float* __restrict__ a, const float* __restrict__ wp,
    const float* __restrict__ bp, float* __restrict__ out) {
  __shared__ __align__(16) float as[64][64];
  __shared__ float wps[64][65];
  int t = threadIdx.x;
  int b = blockIdx.x >> 6;
  int px0 = (blockIdx.x & 63) << 6;
#pragma unroll
  for (int kk = 0; kk < 16; kk++) {
    int idx = kk * 256 + t;
    int c = idx >> 6, px = idx & 63;
    as[c][px] = a[((size_t)b << 18) + ((size_t)c << 12) + px0 + px];
    int o = idx >> 6, c2 = idx & 63;
    wps[c2][o] = wp[idx];
  }
  __syncthreads();

  int o = t & 63;
  int pw = (t >> 6) << 4;
  float acc[16];
#pragma unroll
  for (int p = 0; p < 16; p++) acc[p] = 0.f;
  for (int c = 0; c < 64; c++) {
    float wv = wps[c][o];
    float xr[16];
#pragma unroll
    for (int g = 0; g < 4; g++) {
      float4 x4 = *reinterpret_cast<const float4*>(&as[c][pw + 4 * g]);
      xr[4 * g] = x4.x; xr[4 * g + 1] = x4.y; xr[4 * g + 2] = x4.z; xr[4 * g + 3] = x4.w;
    }
#pragma unroll
    for (int p = 0; p < 16; p++) acc[p] += wv * xr[p];
  }
  float bv = bp[o];
  float* dst = out + ((size_t)(b * 64 + o) << 12) + px0 + pw;
#pragma unroll
  for (int g = 0; g < 4; g++) {
    float4 v4 = { acc[4 * g + 0] + bv, acc[4 * g + 1] + bv,
                  acc[4 * g + 2] + bv, acc[4 * g + 3] + bv };
    reinterpret_cast<float4*>(dst)[g] = v4;
  }
}

extern "C" void kernel_launch(void* const* d_in, const int* in_sizes, int n_in,
                              void* d_out, int out_size, void* d_ws, size_t ws_size,
                              hipStream_t stream) {
  (void)in_sizes; (void)n_in; (void)out_size; (void)ws_size;
  const float* x  = (const float*)d_in[0];
  const float* wq = (const float*)d_in[1];
  const float* bq = (const float*)d_in[2];
  const float* wk = (const float*)d_in[3];
  const float* bk = (const float*)d_in[4];
  const float* wv = (const float*)d_in[5];
  const float* bv = (const float*)d_in[6];
  const float* wp = (const float*)d_in[7];
  const float* bp = (const float*)d_in[8];

  float* ws = (float*)d_ws;
  float* qb = ws;                                   // 1M f32
  unsigned short* kT = (unsigned short*)(ws + (1u << 20));   // 1M bf16
  unsigned short* vT = (unsigned short*)(ws + (1u << 20) + (1u << 19));  // 1M bf16
  float* ao = ws + 2u * (1u << 20);                 // 1M f32

  qkv_proj<<<256, 256, 0, stream>>>(x, wq, bq, wk, bk, wv, bv, qb, kT, vT);
  attn_mfma<<<2048, 256, 0, stream>>>(qb, kT, vT, ao);
  out_proj<<<256, 256, 0, stream>>>(ao, wp, bp, (float*)d_out);
}

// Round 6
// 77.505 us; speedup vs baseline: 1.4808x; 1.4808x over previous
//
#include <hip/hip_runtime.h>

#define LOG2E 1.4426950408889634f

// B=4, C=64, HW=4096, HEADS=4, ch=16
// qT : [bh][i][ch16] f32, scaled by LOG2E
// kT : [bh][j][ch16] bf16 (32B rows)
// vb : [b][o][hw] bf16
// ao : [bh][i][ch16] f32 == raw .view order [b][64][4096]

using s8v   = __attribute__((ext_vector_type(8))) short;
using u16x8 = __attribute__((ext_vector_type(8))) unsigned short;
using f32x4 = __attribute__((ext_vector_type(4))) float;

static __device__ __forceinline__ unsigned short bf16b(float f) {
  return __builtin_bit_cast(unsigned short, (__bf16)f);
}

__global__ __launch_bounds__(256) void qkv_proj(
    const float* __restrict__ x,
    const float* __restrict__ wq, const float* __restrict__ bq,
    const float* __restrict__ wk, const float* __restrict__ bk,
    const float* __restrict__ wv, const float* __restrict__ bv,
    float* __restrict__ qT, unsigned short* __restrict__ kT,
    unsigned short* __restrict__ vb) {
  __shared__ __align__(16) float xs[64][64];     // [c][px]
  __shared__ float wqs[64][65];                  // [c][o] transposed, padded
  __shared__ float wks[64][65];
  __shared__ float wvs[64][65];
  int t = threadIdx.x;
  int b = blockIdx.x >> 6;
  int px0 = (blockIdx.x & 63) << 6;
#pragma unroll
  for (int kk = 0; kk < 16; kk++) {
    int idx = kk * 256 + t;
    int c = idx >> 6, px = idx & 63;
    xs[c][px] = x[((size_t)(b * 64 + c) << 12) + px0 + px];
    int o = idx >> 6, c2 = idx & 63;
    wqs[c2][o] = wq[idx];
    wks[c2][o] = wk[idx];
    wvs[c2][o] = wv[idx];
  }
  __syncthreads();

  int o = t & 63;
  int pw = (t >> 6) << 4;
  float aq[16], ak[16], av[16];
#pragma unroll
  for (int p = 0; p < 16; p++) { aq[p] = 0.f; ak[p] = 0.f; av[p] = 0.f; }

  for (int c = 0; c < 64; c++) {
    float wqv = wqs[c][o], wkv = wks[c][o], wvv = wvs[c][o];
    float xr[16];
#pragma unroll
    for (int g = 0; g < 4; g++) {
      float4 x4 = *reinterpret_cast<const float4*>(&xs[c][pw + 4 * g]);
      xr[4 * g] = x4.x; xr[4 * g + 1] = x4.y; xr[4 * g + 2] = x4.z; xr[4 * g + 3] = x4.w;
    }
#pragma unroll
    for (int p = 0; p < 16; p++) {
      aq[p] += wqv * xr[p];
      ak[p] += wkv * xr[p];
      av[p] += wvv * xr[p];
    }
  }

  float bqv = bq[o], bkv = bk[o], bvv = bv[o];
  {
    // v: bf16 [b][o][hw]
    unsigned short* dstv = vb + ((size_t)(b * 64 + o) << 12) + px0 + pw;
    u16x8 v0, v1;
#pragma unroll
    for (int p = 0; p < 8; p++) {
      v0[p] = bf16b(av[p] + bvv);
      v1[p] = bf16b(av[8 + p] + bvv);
    }
    *reinterpret_cast<u16x8*>(dstv) = v0;
    *reinterpret_cast<u16x8*>(dstv + 8) = v1;
  }
  // q: f32 [bh][i][ch], scaled; k: bf16 [bh][j][ch]
  int bh = b * 4 + (o >> 4);
  int chn = o & 15;
  size_t kb = ((size_t)bh << 16) + ((size_t)(px0 + pw) << 4) + chn;
#pragma unroll
  for (int p = 0; p < 16; p++) {
    qT[kb + ((size_t)p << 4)] = (aq[p] + bqv) * LOG2E;
    kT[kb + ((size_t)p << 4)] = bf16b(ak[p] + bkv);
  }
}

// MFMA flash attention, no max tracking (scores bounded; fixed M=0 softmax is
// exact in f32 range). grid = 1024 (16 bh x 64 i-tiles), 4 waves/block; wave w
// owns j-slice [w*1024, w*1024+1024).
// Swapped QK^T: S^T = mfma(Kdup, [Qhi|Qlo]) -> lane(i_,q4) holds
// s0[r]=S[jb+4q4+r][i_], s1[r]=S[jb+16+4q4+r][i_].
// PV k-slot perm perm(8q4+e)= e<4 ? 4q4+e : 16+4q4+e-4 on BOTH V-A and P-B
// fragments -> P B-frag is the lane's own exp values; zero cross-lane traffic.
// L-sum via ones-MFMA: accl = mfma(ones, PB, accl) sums all 32 k-slots of P
// per query column -> full per-query l, no VALU adds, no shuffles.
__global__ __launch_bounds__(256) void attn_mfma(
    const float* __restrict__ qT, const unsigned short* __restrict__ kT,
    const unsigned short* __restrict__ vb, float* __restrict__ ao) {
  __shared__ float red[4][64][18];
  const int tid  = threadIdx.x;
  const int w    = tid >> 6;
  const int lane = tid & 63;
  const int i_   = lane & 15;
  const int q4   = lane >> 4;
  const int chb  = (q4 & 1) << 3;

  // XCD swizzle: 2 bh per XCD
  const int orig = ((blockIdx.x & 7) << 7) + (blockIdx.x >> 3);
  const int bh = orig >> 6;
  const int i0 = (orig & 63) << 6;
  const int b = bh >> 2, h = bh & 3;

  // Q fragments: B[k][n]: lane holds col n=i_, k = 8*q4+e.
  // k 0-15 -> Qhi (q4<2), k 16-31 -> Qlo (q4>=2); ch = chb+e.
  s8v BQ[4];
#pragma unroll
  for (int g = 0; g < 4; ++g) {
    const float* qp = qT + ((size_t)bh << 16) + ((size_t)(i0 + (g << 4) + i_) << 4) + chb;
    float4 f0 = *(const float4*)qp;
    float4 f1 = *(const float4*)(qp + 4);
    float fr[8] = { f0.x, f0.y, f0.z, f0.w, f1.x, f1.y, f1.z, f1.w };
#pragma unroll
    for (int e = 0; e < 8; ++e) {
      float f = fr[e];
      __bf16 hi = (__bf16)f;
      float v = (q4 < 2) ? (float)hi : (f - (float)hi);
      BQ[g][e] = __builtin_bit_cast(short, (__bf16)v);
    }
  }

  s8v ones;
#pragma unroll
  for (int e = 0; e < 8; ++e) ones[e] = (short)0x3F80;  // bf16 1.0

  f32x4 acc[4], accl[4];
#pragma unroll
  for (int g = 0; g < 4; ++g) {
    acc[g] = (f32x4){0.f, 0.f, 0.f, 0.f};
    accl[g] = (f32x4){0.f, 0.f, 0.f, 0.f};
  }

  const unsigned short* vpb = vb + (((size_t)(b * 64 + h * 16 + i_)) << 12);
  const unsigned short* kpb = kT + ((size_t)bh << 16);

  // prefetch t=0
  s8v AV, AK0, AK1;
  {
    const int jb = (w << 10);
    struct { uint2 a, b; } pair;
    pair.a = *(const uint2*)(vpb + jb + (q4 << 2));
    pair.b = *(const uint2*)(vpb + jb + 16 + (q4 << 2));
    AV = __builtin_bit_cast(s8v, pair);
    AK0 = *(const s8v*)(kpb + (((size_t)(jb + i_)) << 4) + chb);
    AK1 = *(const s8v*)(kpb + (((size_t)(jb + 16 + i_)) << 4) + chb);
  }

  for (int t = 0; t < 32; ++t) {
    // prefetch t+1 (wrap: last iter redundantly reloads t=0, L2-hit, branchless)
    s8v nAV, nAK0, nAK1;
    {
      const int jn = (w << 10) + (((t + 1) & 31) << 5);
      struct { uint2 a, b; } pair;
      pair.a = *(const uint2*)(vpb + jn + (q4 << 2));
      pair.b = *(const uint2*)(vpb + jn + 16 + (q4 << 2));
      nAV = __builtin_bit_cast(s8v, pair);
      nAK0 = *(const s8v*)(kpb + (((size_t)(jn + i_)) << 4) + chb);
      nAK1 = *(const s8v*)(kpb + (((size_t)(jn + 16 + i_)) << 4) + chb);
    }

#pragma unroll
    for (int g = 0; g < 4; ++g) {
      f32x4 z = {0.f, 0.f, 0.f, 0.f};
      f32x4 s0 = __builtin_amdgcn_mfma_f32_16x16x32_bf16(AK0, BQ[g], z, 0, 0, 0);
      f32x4 s1 = __builtin_amdgcn_mfma_f32_16x16x32_bf16(AK1, BQ[g], z, 0, 0, 0);
      float p0 = __builtin_amdgcn_exp2f(s0[0]);
      float p1 = __builtin_amdgcn_exp2f(s0[1]);
      float p2 = __builtin_amdgcn_exp2f(s0[2]);
      float p3 = __builtin_amdgcn_exp2f(s0[3]);
      float p4 = __builtin_amdgcn_exp2f(s1[0]);
      float p5 = __builtin_amdgcn_exp2f(s1[1]);
      float p6 = __builtin_amdgcn_exp2f(s1[2]);
      float p7 = __builtin_amdgcn_exp2f(s1[3]);
      // P B-frag: lane col i_, k=8q4+e -> P[jb+perm][i_] = own p values, in order
      s8v PB;
      PB[0] = (short)bf16b(p0); PB[1] = (short)bf16b(p1);
      PB[2] = (short)bf16b(p2); PB[3] = (short)bf16b(p3);
      PB[4] = (short)bf16b(p4); PB[5] = (short)bf16b(p5);
      PB[6] = (short)bf16b(p6); PB[7] = (short)bf16b(p7);
      acc[g]  = __builtin_amdgcn_mfma_f32_16x16x32_bf16(AV, PB, acc[g], 0, 0, 0);
      accl[g] = __builtin_amdgcn_mfma_f32_16x16x32_bf16(ones, PB, accl[g], 0, 0, 0);
    }
    AV = nAV; AK0 = nAK0; AK1 = nAK1;
  }

  // per-wave results -> LDS merge across the 4 j-slices (pure sums)
#pragma unroll
  for (int g = 0; g < 4; ++g) {
    int iq = (g << 4) + i_;
    if (q4 == 0) red[w][iq][0] = accl[g][0];   // all rows/lanes of accl identical per query
    red[w][iq][1 + (q4 << 2) + 0] = acc[g][0];
    red[w][iq][1 + (q4 << 2) + 1] = acc[g][1];
    red[w][iq][1 + (q4 << 2) + 2] = acc[g][2];
    red[w][iq][1 + (q4 << 2) + 3] = acc[g][3];
  }
  __syncthreads();

  {
    int iq = tid & 63, quad = tid >> 6;
    float L = (red[0][iq][0] + red[1][iq][0]) + (red[2][iq][0] + red[3][iq][0]);
    float o0 = 0.f, o1 = 0.f, o2 = 0.f, o3 = 0.f;
#pragma unroll
    for (int s = 0; s < 4; ++s) {
      o0 += red[s][iq][1 + (quad << 2) + 0];
      o1 += red[s][iq][1 + (quad << 2) + 1];
      o2 += red[s][iq][1 + (quad << 2) + 2];
      o3 += red[s][iq][1 + (quad << 2) + 3];
    }
    float inv = 1.0f / L;
    float4 o = { o0 * inv, o1 * inv, o2 * inv, o3 * inv };
    *(float4*)&ao[((((size_t)bh << 12) + i0 + iq) << 4) + (quad << 2)] = o;
  }
}

__global__ __launch_bounds__(256) void out_proj(
    const float* __restrict__ a, const float* __restrict__ wp,
    const float* __restrict__ bp, float* __restrict__ out) {
  __shared__ __align__(16) float as[64][64];
  __shared__ float wps[64][65];
  int t = threadIdx.x;
  int b = blockIdx.x >> 6;
  int px0 = (blockIdx.x & 63) << 6;
#pragma unroll
  for (int kk = 0; kk < 16; kk++) {
    int idx = kk * 256 + t;
    int c = idx >> 6, px = idx & 63;
    as[c][px] = a[((size_t)b << 18) + ((size_t)c << 12) + px0 + px];
    int o = idx >> 6, c2 = idx & 63;
    wps[c2][o] = wp[idx];
  }
  __syncthreads();

  int o = t & 63;
  int pw = (t >> 6) << 4;
  float acc[16];
#pragma unroll
  for (int p = 0; p < 16; p++) acc[p] = 0.f;
  for (int c = 0; c < 64; c++) {
    float wv = wps[c][o];
    float xr[16];
#pragma unroll
    for (int g = 0; g < 4; g++) {
      float4 x4 = *reinterpret_cast<const float4*>(&as[c][pw + 4 * g]);
      xr[4 * g] = x4.x; xr[4 * g + 1] = x4.y; xr[4 * g + 2] = x4.z; xr[4 * g + 3] = x4.w;
    }
#pragma unroll
    for (int p = 0; p < 16; p++) acc[p] += wv * xr[p];
  }
  float bv = bp[o];
  float* dst = out + ((size_t)(b * 64 + o) << 12) + px0 + pw;
#pragma unroll
  for (int g = 0; g < 4; g++) {
    float4 v4 = { acc[4 * g + 0] + bv, acc[4 * g + 1] + bv,
                  acc[4 * g + 2] + bv, acc[4 * g + 3] + bv };
    reinterpret_cast<float4*>(dst)[g] = v4;
  }
}

extern "C" void kernel_launch(void* const* d_in, const int* in_sizes, int n_in,
                              void* d_out, int out_size, void* d_ws, size_t ws_size,
                              hipStream_t stream) {
  (void)in_sizes; (void)n_in; (void)out_size; (void)ws_size;
  const float* x  = (const float*)d_in[0];
  const float* wq = (const float*)d_in[1];
  const float* bq = (const float*)d_in[2];
  const float* wk = (const float*)d_in[3];
  const float* bk = (const float*)d_in[4];
  const float* wv = (const float*)d_in[5];
  const float* bv = (const float*)d_in[6];
  const float* wp = (const float*)d_in[7];
  const float* bp = (const float*)d_in[8];

  float* ws = (float*)d_ws;
  float* qT = ws;                                   // 1M f32 [bh][i][ch]
  unsigned short* kT = (unsigned short*)(ws + (1u << 20));   // 1M bf16
  unsigned short* vT = (unsigned short*)(ws + (1u << 20) + (1u << 19));  // 1M bf16
  float* ao = ws + 2u * (1u << 20);                 // 1M f32

  qkv_proj<<<256, 256, 0, stream>>>(x, wq, bq, wk, bk, wv, bv, qT, kT, vT);
  attn_mfma<<<1024, 256, 0, stream>>>(qT, kT, vT, ao);
  out_proj<<<256, 256, 0, stream>>>(ao, wp, bp, (float*)d_out);
}